// Round 9
// baseline (379.847 us; speedup 1.0000x reference)
//
#include <hip/hip_runtime.h>
#include <hip/hip_bf16.h>

// PropNet fused MFMA-bf16 implementation for MI355X (gfx950).
// B=2 N=64 R=16 D=64 H=256 EOUT=64 PSTEP=2
// node rows nr = (b*64+i)*16 + r            (2048)
// edge rows er = ((b*64+i)*64 + j)*16 + r   (131072)
//
// R8 lesson: barrier-merging was neutral; real costs were (a) per-block
// weight re-streaming from L2 (32-row blocks -> 2.5GB, ~72us floor),
// (b) 32 scalar ds_write_b16 per thread per epilogue, (c) bank conflicts.
// R9: OPERAND SWAP — compute C^T = W^T(A) * X^T(B). Weight fragments and
// LDS reads are bit-identical (kmap cancellation preserved); the C/D map
// now gives each lane 4 CONSECUTIVE OUT-COLS of one row:
//  - epilogues: 8x ds_write_b64 packed (was 32x ds_write_b16)
//  - E1b/E2/bias reads and final out stores become float4/dwordx4
//  - blocks cover 64 rows with 8 waves (512 thr), acc[2][4]=32 VGPR:
//    2048 blocks, weight L2 traffic HALVED, agg per-block (no partials).
//
// All GEMMs: v_mfma_f32_16x16x32_bf16. Weights pre-packed into fragment
// order with the SAME (lane,elem)->k map as the LDS B-fragment reads, so
// any k-map mismatch vs HW cancels. LDS tiles XOR-swizzled:
// byte ^= (row&7)<<4.

typedef __attribute__((ext_vector_type(8))) short short8;
typedef __attribute__((ext_vector_type(4))) float f32x4;
typedef __attribute__((ext_vector_type(2))) unsigned int u32x2;

#define DI __device__ __forceinline__

// ---------------- workspace layout (bytes) ----------------
constexpr size_t WF_SZ = 131072;            // 256x256 bf16 frag matrix
// 0 ep0W1c 1 ep0W2 2 ep1W1c 3 ep1W2 4 prW1a 5 prW1b 6 E1w 7 E2w
// 8 NE2w 9 NAGGw 10 NE1w 11 npW2 12 ep1Aw 13 ep1Bw
constexpr size_t OFF_NEW  = 14 * WF_SZ;      // neW 64x256 frag
constexpr size_t OFF_EE1  = OFF_NEW + 32768;
constexpr size_t OFF_EE2  = OFF_EE1 + 32768;
constexpr size_t OFF_PW2  = OFF_EE2 + 32768;
constexpr size_t OFF_NENC = OFF_PW2 + 32768; // node_enc bf16 [2048,256]
constexpr size_t OFF_X1   = OFF_NENC + (size_t)2048 * 256 * 2;
constexpr size_t SM = (size_t)2048 * 256 * 4;
constexpr size_t OFF_X2   = OFF_X1 + SM;
constexpr size_t OFF_E1   = OFF_X2 + SM;      // E1b = E1 + b1
constexpr size_t OFF_E2   = OFF_E1 + SM;      // E2 f32 [2048][256]
constexpr size_t OFF_NE1  = OFF_E2 + SM;
constexpr size_t OFF_AGG  = OFF_NE1 + SM;     // single [2048][256] f32
constexpr size_t OFF_IMG  = OFF_AGG + SM;     // eff images: 2048 x 32KB
// total ~80 MB

DI unsigned short f2bf(float f) {
    unsigned u = __builtin_bit_cast(unsigned, f);
    u += 0x7fffu + ((u >> 16) & 1u);
    return (unsigned short)(u >> 16);
}

DI int kmap(int g, int e) { return 4 * g + (e & 3) + ((e >> 2) << 4); }

DI void dma16(const void* g, void* l) {
    __builtin_amdgcn_global_load_lds((const __attribute__((address_space(1))) void*)g,
                                     (__attribute__((address_space(3))) void*)l, 16, 0, 0);
}

// pack 4 f32 (consecutive cols) to bf16x4 and store as b64
DI void pack_store(unsigned char* buf, int row, int col0, f32x4 v) {
    int byte = row * 512 + ((col0 * 2) ^ ((row & 7) << 4));
    u32x2 pk;
    pk[0] = (unsigned)f2bf(v[0]) | ((unsigned)f2bf(v[1]) << 16);
    pk[1] = (unsigned)f2bf(v[2]) | ((unsigned)f2bf(v[3]) << 16);
    *(u32x2*)(buf + byte) = pk;
}

// ---------------- weight repack: f32 [K x ld] -> bf16 fragment order ----------------
__global__ __launch_bounds__(64) void kconv(const float* ep0W1, const float* ep0W2,
                                            const float* ep1W1, const float* ep1W2,
                                            const float* prW1, const float* prW2,
                                            const float* npW1, const float* npW2,
                                            const float* neW, const float* eeW,
                                            unsigned short* wsu)
{
    int bid = blockIdx.x, l = threadIdx.x;
    const float* src; unsigned short* dst; int NT = 16, ld = 256, f;
    if (bid < 1792) {
        int m = bid >> 7; f = bid & 127;
        switch (m) {
            case 0:  src = ep0W1 + 512 * 256; break;
            case 1:  src = ep0W2;             break;
            case 2:  src = ep1W1 + 512 * 256; break;
            case 3:  src = ep1W2;             break;
            case 4:  src = prW1;              break;
            case 5:  src = prW1 + 256 * 256;  break;
            case 6:  src = ep0W1;             break;
            case 7:  src = ep0W1 + 256 * 256; break;
            case 8:  src = npW1 + 256 * 256;  break;
            case 9:  src = npW1 + 512 * 256;  break;
            case 10: src = npW1;              break;
            case 11: src = npW2;              break;
            case 12: src = ep1W1;             break;
            default: src = ep1W1 + 256 * 256; break;
        }
        dst = wsu + (size_t)m * (WF_SZ / 2);
    } else if (bid < 1888) {
        int m = (bid - 1792) >> 5; f = (bid - 1792) & 31;
        src = (m == 0) ? neW : (m == 1) ? eeW : eeW + 64 * 256;
        dst = wsu + ((m == 0) ? OFF_NEW : (m == 1) ? OFF_EE1 : OFF_EE2) / 2;
    } else {
        f = bid - 1888; NT = 4; ld = 64; src = prW2; dst = wsu + OFF_PW2 / 2;
    }
    int kt = f / NT, nt = f % NT;
    int g = l >> 4, c = nt * 16 + (l & 15);
    unsigned short* o = dst + (size_t)((kt * NT + nt) * 64 + l) * 8;
#pragma unroll
    for (int e = 0; e < 8; ++e) {
        int k = 32 * kt + kmap(g, e);
        o[e] = f2bf(src[(size_t)k * ld + c]);
    }
}

// ---------------- MFMA tile helpers ----------------
template <int LDB>
DI short8 load_afrag(const unsigned char* lds, int row, int kt, int g) {
    int sw = (row & 7) << 4;
    int kb = 64 * kt + 8 * g;
    union { short8 s; u32x2 u[2]; } u_;
    u_.u[0] = *(const u32x2*)(lds + row * LDB + (kb ^ sw));
    u_.u[1] = *(const u32x2*)(lds + row * LDB + ((kb + 32) ^ sw));
    return u_.s;
}

template <int MI>
DI void zero_acc(f32x4 (&acc)[MI][4]) {
#pragma unroll
    for (int mi = 0; mi < MI; ++mi)
#pragma unroll
        for (int ni = 0; ni < 4; ++ni) acc[mi][ni] = (f32x4){0.f, 0.f, 0.f, 0.f};
}

// old-style gemm (node kernels): acc += Atile @ W; wave wv owns cols 64wv..+63
template <int MI, int KT, int LDB>
DI void gemm_tile(const unsigned char* lds, const unsigned short* Wf,
                  f32x4 (&acc)[MI][4], int wv, int l) {
    const int g = l >> 4, l15 = l & 15;
    for (int kt = 0; kt < KT; ++kt) {
        short8 af[MI];
#pragma unroll
        for (int mi = 0; mi < MI; ++mi) af[mi] = load_afrag<LDB>(lds, 16 * mi + l15, kt, g);
        short8 bf[4];
#pragma unroll
        for (int ni = 0; ni < 4; ++ni)
            bf[ni] = *(const short8*)(Wf + (size_t)((kt * 16 + 4 * wv + ni) * 64 + l) * 8);
#pragma unroll
        for (int ni = 0; ni < 4; ++ni)
#pragma unroll
            for (int mi = 0; mi < MI; ++mi)
                acc[mi][ni] = __builtin_amdgcn_mfma_f32_16x16x32_bf16(af[mi], bf[ni], acc[mi][ni], 0, 0, 0);
    }
}

// swapped gemm (edge kernels): C^T = W^T(A) * X^T(B). 64-row tile in LDS;
// wave wv owns out-cols 32wv..+31 (m-tiles 2wv, 2wv+1) x all 64 rows (4 n-tiles).
// acc[mt][nt]: lane&15 = tile row within n-tile, q = out-col within 4g+q.
DI void gemmT(const unsigned char* lds, const unsigned short* Wf,
              f32x4 (&acc)[2][4], int wv, int l) {
    const int g = l >> 4, l15 = l & 15;
    for (int kt = 0; kt < 8; ++kt) {
        short8 bfr[4];
#pragma unroll
        for (int nt = 0; nt < 4; ++nt) bfr[nt] = load_afrag<512>(lds, 16 * nt + l15, kt, g);
        short8 wfr[2];
#pragma unroll
        for (int mt = 0; mt < 2; ++mt)
            wfr[mt] = *(const short8*)(Wf + (size_t)((kt * 16 + 2 * wv + mt) * 64 + l) * 8);
#pragma unroll
        for (int mt = 0; mt < 2; ++mt)
#pragma unroll
            for (int nt = 0; nt < 4; ++nt)
                acc[mt][nt] = __builtin_amdgcn_mfma_f32_16x16x32_bf16(wfr[mt], bfr[nt], acc[mt][nt], 0, 0, 0);
    }
}

template <int MI>
DI void store_tile_f32(float* dst, int r0, f32x4 (&acc)[MI][4], int wv, int l) {
    int g = l >> 4, l15 = l & 15;
#pragma unroll
    for (int ni = 0; ni < 4; ++ni) {
        int col = 64 * wv + 16 * ni + l15;
#pragma unroll
        for (int mi = 0; mi < MI; ++mi)
#pragma unroll
            for (int q = 0; q < 4; ++q)
                dst[(size_t)(r0 + 16 * mi + 4 * g + q) * 256 + col] = acc[mi][ni][q];
    }
}

template <int MI>
DI void store_tile_bias(float* dst, const float* bias, int r0, f32x4 (&acc)[MI][4], int wv, int l) {
    int g = l >> 4, l15 = l & 15;
#pragma unroll
    for (int ni = 0; ni < 4; ++ni) {
        int col = 64 * wv + 16 * ni + l15;
        float bb = bias[col];
#pragma unroll
        for (int mi = 0; mi < MI; ++mi)
#pragma unroll
            for (int q = 0; q < 4; ++q)
                dst[(size_t)(r0 + 16 * mi + 4 * g + q) * 256 + col] = acc[mi][ni][q] + bb;
    }
}

// ---------------- node path: encoder + edge-enc partials + E1b/E2/NE1 ----------------
__global__ __launch_bounds__(256) void knode12(const float* node_rep, const float* neb,
        const float* ep0b1,
        const unsigned short* neWf, const unsigned short* eeW1f, const unsigned short* eeW2f,
        const unsigned short* E1wf, const unsigned short* E2wf, const unsigned short* NE1wf,
        unsigned short* node_enc, float* X1, float* X2, float* E1b, float* E2, float* NE1)
{
    __shared__ __align__(16) unsigned char ldsA[32 * 128];
    __shared__ __align__(16) unsigned char ldsB[32 * 512];
    const int r0 = blockIdx.x * 32, tid = threadIdx.x;
    {
        int row = tid >> 3, c0 = (tid & 7) * 8;
        const float* src = node_rep + (size_t)(r0 + row) * 64 + c0;
        union { short8 s; unsigned short u[8]; } v;
#pragma unroll
        for (int e = 0; e < 8; ++e) v.u[e] = f2bf(src[e]);
        *(short8*)&ldsA[row * 128 + ((c0 * 2) ^ ((row & 7) << 4))] = v.s;
    }
    __syncthreads();
    const int l = tid & 63, wv = tid >> 6, g = l >> 4, l15 = l & 15;
    f32x4 acc[2][4];
    zero_acc(acc);
    gemm_tile<2, 2, 128>(ldsA, neWf, acc, wv, l);
#pragma unroll
    for (int ni = 0; ni < 4; ++ni) {
        int col = 64 * wv + 16 * ni + l15;
        float bb = neb[col];
#pragma unroll
        for (int mi = 0; mi < 2; ++mi)
#pragma unroll
            for (int q = 0; q < 4; ++q) {
                int row = 16 * mi + 4 * g + q;
                unsigned short bv = f2bf(fmaxf(acc[mi][ni][q] + bb, 0.f));
                *(unsigned short*)&ldsB[row * 512 + ((col * 2) ^ ((row & 7) << 4))] = bv;
                node_enc[(size_t)(r0 + row) * 256 + col] = bv;
            }
    }
    zero_acc(acc);
    gemm_tile<2, 2, 128>(ldsA, eeW1f, acc, wv, l);
    store_tile_f32<2>(X1, r0, acc, wv, l);
    zero_acc(acc);
    gemm_tile<2, 2, 128>(ldsA, eeW2f, acc, wv, l);
    store_tile_f32<2>(X2, r0, acc, wv, l);
    __syncthreads();
    zero_acc(acc);
    gemm_tile<2, 8, 512>(ldsB, E1wf, acc, wv, l);
    store_tile_bias<2>(E1b, ep0b1, r0, acc, wv, l);
    zero_acc(acc);
    gemm_tile<2, 8, 512>(ldsB, E2wf, acc, wv, l);
    store_tile_f32<2>(E2, r0, acc, wv, l);
    zero_acc(acc);
    gemm_tile<2, 8, 512>(ldsB, NE1wf, acc, wv, l);
    store_tile_f32<2>(NE1, r0, acc, wv, l);
}

// ---------------- node update chain (step-1) + E1b_1/E2_1 ----------------
__global__ __launch_bounds__(256) void knode3(const unsigned short* node_enc, const float* agg,
        const float* NE1, const float* npb1, const float* npb2, const float* ep1b1,
        const unsigned short* NE2wf, const unsigned short* NAGGwf, const unsigned short* npW2f,
        const unsigned short* ep1Awf, const unsigned short* ep1Bwf,
        float* E1b, float* E2)
{
    __shared__ __align__(16) unsigned char ldsA[32 * 512];
    __shared__ __align__(16) unsigned char ldsB[32 * 512];
    const int r0 = blockIdx.x * 32, tid = threadIdx.x;
    {
        int row = tid >> 3, cbase = (tid & 7) * 32;
        int sw = (row & 7) << 4;
#pragma unroll
        for (int cc = 0; cc < 2; ++cc) {
            int c0 = cbase + cc * 16;
            short8 lo = *(const short8*)(node_enc + (size_t)(r0 + row) * 256 + c0);
            short8 hi = *(const short8*)(node_enc + (size_t)(r0 + row) * 256 + c0 + 8);
            *(short8*)&ldsA[row * 512 + ((c0 * 2) ^ sw)] = lo;
            *(short8*)&ldsA[row * 512 + ((c0 * 2 + 16) ^ sw)] = hi;
            union { short8 s; unsigned short u[8]; } v0, v1;
            const float* aA = agg + (size_t)(r0 + row) * 256 + c0;
#pragma unroll
            for (int e = 0; e < 8; ++e) {
                v0.u[e] = f2bf(aA[e]);
                v1.u[e] = f2bf(aA[8 + e]);
            }
            *(short8*)&ldsB[row * 512 + ((c0 * 2) ^ sw)] = v0.s;
            *(short8*)&ldsB[row * 512 + ((c0 * 2 + 16) ^ sw)] = v1.s;
        }
    }
    __syncthreads();
    const int l = tid & 63, wv = tid >> 6, g = l >> 4, l15 = l & 15;
    f32x4 acc[2][4];
    zero_acc(acc);
    gemm_tile<2, 8, 512>(ldsA, NE2wf, acc, wv, l);
    gemm_tile<2, 8, 512>(ldsB, NAGGwf, acc, wv, l);
    __syncthreads();
#pragma unroll
    for (int ni = 0; ni < 4; ++ni) {
        int col = 64 * wv + 16 * ni + l15;
        float bb = npb1[col];
#pragma unroll
        for (int mi = 0; mi < 2; ++mi)
#pragma unroll
            for (int q = 0; q < 4; ++q) {
                int row = 16 * mi + 4 * g + q;
                float v = fmaxf(acc[mi][ni][q] + NE1[(size_t)(r0 + row) * 256 + col] + bb, 0.f);
                *(unsigned short*)&ldsA[row * 512 + ((col * 2) ^ ((row & 7) << 4))] = f2bf(v);
            }
    }
    __syncthreads();
    zero_acc(acc);
    gemm_tile<2, 8, 512>(ldsA, npW2f, acc, wv, l);
    __syncthreads();
#pragma unroll
    for (int ni = 0; ni < 4; ++ni) {
        int col = 64 * wv + 16 * ni + l15;
        float bb = npb2[col];
#pragma unroll
        for (int mi = 0; mi < 2; ++mi)
#pragma unroll
            for (int q = 0; q < 4; ++q) {
                int row = 16 * mi + 4 * g + q;
                *(unsigned short*)&ldsB[row * 512 + ((col * 2) ^ ((row & 7) << 4))] =
                    f2bf(fmaxf(acc[mi][ni][q] + bb, 0.f));
            }
    }
    __syncthreads();
    zero_acc(acc);
    gemm_tile<2, 8, 512>(ldsB, ep1Awf, acc, wv, l);
    store_tile_bias<2>(E1b, ep1b1, r0, acc, wv, l);
    zero_acc(acc);
    gemm_tile<2, 8, 512>(ldsB, ep1Bwf, acc, wv, l);
    store_tile_f32<2>(E2, r0, acc, wv, l);
}

// ---------------- fused edge propagation step 0 (64-row blocks, operand-swap) ----------------
__global__ __launch_bounds__(512, 2) void kstep1(const float* X1, const float* X2, const float* eeb,
                                                 const float* E1b, const float* E2, const float* b2,
                                                 const unsigned short* WfA, const unsigned short* WfB,
                                                 unsigned char* img, float* agg)
{
    __shared__ __align__(16) unsigned char T[64 * 512];
    __shared__ __align__(16) unsigned char U[64 * 512];
    const int bir = blockIdx.x, tid = threadIdx.x;
    const int b = bir >> 10, r = bir & 15;
    const int l = tid & 63, wv = tid >> 6, g = l >> 4, l15 = l & 15;

    // phase 0: e0 -> T (rows = senders j = 0..63)
    {
        int row = tid >> 3, cb = (tid & 7) * 32;
        for (int cc = 0; cc < 4; ++cc) {
            int c0 = cb + cc * 8;
            union { short8 s; unsigned short u[8]; } v;
            int nrj = b * 1024 + row * 16 + r;
#pragma unroll
            for (int e = 0; e < 8; ++e) {
                float x = X1[(size_t)bir * 256 + c0 + e] + X2[(size_t)nrj * 256 + c0 + e] + eeb[c0 + e];
                v.u[e] = f2bf(fmaxf(x, 0.f));
            }
            *(short8*)&T[row * 512 + ((c0 * 2) ^ ((row & 7) << 4))] = v.s;
        }
    }
    __syncthreads();

    f32x4 acc[2][4];
    zero_acc(acc);
    gemmT(T, WfA, acc, wv, l);
    // h-epi -> U (E1b/E2 float4 loads; 8 packed b64 stores)
#pragma unroll
    for (int mt = 0; mt < 2; ++mt) {
        int col0 = 32 * wv + 16 * mt + 4 * g;
        f32x4 e1v = *(const f32x4*)&E1b[(size_t)bir * 256 + col0];
#pragma unroll
        for (int nt = 0; nt < 4; ++nt) {
            int row = 16 * nt + l15;
            f32x4 e2v = *(const f32x4*)&E2[(size_t)(b * 1024 + row * 16 + r) * 256 + col0];
            f32x4 h;
#pragma unroll
            for (int q = 0; q < 4; ++q) h[q] = fmaxf(acc[mt][nt][q] + e1v[q] + e2v[q], 0.f);
            pack_store(U, row, col0, h);
            acc[mt][nt] = (f32x4){0.f, 0.f, 0.f, 0.f};
        }
    }
    __syncthreads();
    gemmT(U, WfB, acc, wv, l);
    // eff-epi -> img (packed b64 global) + agg (full j-sum per block)
    unsigned char* imgb = img + (size_t)bir * 32768;
#pragma unroll
    for (int mt = 0; mt < 2; ++mt) {
        int col0 = 32 * wv + 16 * mt + 4 * g;
        f32x4 b2v = *(const f32x4*)&b2[col0];
        f32x4 s = (f32x4){0.f, 0.f, 0.f, 0.f};
#pragma unroll
        for (int nt = 0; nt < 4; ++nt) {
            int row = 16 * nt + l15;
            f32x4 ev;
#pragma unroll
            for (int q = 0; q < 4; ++q) ev[q] = fmaxf(acc[mt][nt][q] + b2v[q], 0.f);
            int byte = row * 512 + ((col0 * 2) ^ ((row & 7) << 4));
            u32x2 pk;
            pk[0] = (unsigned)f2bf(ev[0]) | ((unsigned)f2bf(ev[1]) << 16);
            pk[1] = (unsigned)f2bf(ev[2]) | ((unsigned)f2bf(ev[3]) << 16);
            *(u32x2*)(imgb + byte) = pk;
            s += ev;
        }
#pragma unroll
        for (int m = 1; m <= 8; m <<= 1)
#pragma unroll
            for (int q = 0; q < 4; ++q) s[q] += __shfl_xor(s[q], m);
        if (l15 == 0) *(f32x4*)&agg[(size_t)bir * 256 + col0] = s;
    }
}

// ---------------- fused edge step 1 + predictor (64-row blocks, operand-swap) ----------------
__global__ __launch_bounds__(512, 2) void kstep2pred(const float* X1, const float* X2, const float* eeb,
        const float* E1b, const float* E2, const float* b2,
        const unsigned short* WfA, const unsigned short* WfB,
        const unsigned short* WfPA, const unsigned short* WfPB, const unsigned short* WfP2,
        const float* prb1, const float* prb2,
        const unsigned char* img, float* out)
{
    __shared__ __align__(16) unsigned char T[64 * 512];
    __shared__ __align__(16) unsigned char U[64 * 512];
    const int bir = blockIdx.x, tid = threadIdx.x;
    const int b = bir >> 10, r = bir & 15;
    const int ebase = (bir >> 4) * 1024 + r;
    const int l = tid & 63, wv = tid >> 6, g = l >> 4, l15 = l & 15;

    // phase 0: DMA eff image -> T (32KB, 8 waves x 4 chunks)
    {
        const unsigned char* src = img + (size_t)bir * 32768;
#pragma unroll
        for (int p = 0; p < 4; ++p) {
            int chunk = wv * 4 + p;
            dma16(src + chunk * 1024 + l * 16, &T[chunk * 1024]);
        }
    }
    __syncthreads();

    f32x4 acc[2][4];
    // phase 1: WfA(T) + h-epi -> U
    zero_acc(acc);
    gemmT(T, WfA, acc, wv, l);
#pragma unroll
    for (int mt = 0; mt < 2; ++mt) {
        int col0 = 32 * wv + 16 * mt + 4 * g;
        f32x4 e1v = *(const f32x4*)&E1b[(size_t)bir * 256 + col0];
#pragma unroll
        for (int nt = 0; nt < 4; ++nt) {
            int row = 16 * nt + l15;
            f32x4 e2v = *(const f32x4*)&E2[(size_t)(b * 1024 + row * 16 + r) * 256 + col0];
            f32x4 h;
#pragma unroll
            for (int q = 0; q < 4; ++q) h[q] = fmaxf(acc[mt][nt][q] + e1v[q] + e2v[q], 0.f);
            pack_store(U, row, col0, h);
            acc[mt][nt] = (f32x4){0.f, 0.f, 0.f, 0.f};
        }
    }
    __syncthreads();
    // phase 2: WfB(U) + eff2-epi -> T
    gemmT(U, WfB, acc, wv, l);
#pragma unroll
    for (int mt = 0; mt < 2; ++mt) {
        int col0 = 32 * wv + 16 * mt + 4 * g;
        f32x4 b2v = *(const f32x4*)&b2[col0];
#pragma unroll
        for (int nt = 0; nt < 4; ++nt) {
            int row = 16 * nt + l15;
            f32x4 ev;
#pragma unroll
            for (int q = 0; q < 4; ++q) ev[q] = fmaxf(acc[mt][nt][q] + b2v[q], 0.f);
            pack_store(T, row, col0, ev);
            acc[mt][nt] = (f32x4){0.f, 0.f, 0.f, 0.f};
        }
    }
    __syncthreads();
    // phase 3: WfPA(T) + e0-rebuild -> U
    gemmT(T, WfPA, acc, wv, l);
    {
        int row = tid >> 3, cb = (tid & 7) * 32;
        for (int cc = 0; cc < 4; ++cc) {
            int c0 = cb + cc * 8;
            union { short8 s; unsigned short u[8]; } v;
            int nrj = b * 1024 + row * 16 + r;
#pragma unroll
            for (int e = 0; e < 8; ++e) {
                float x = X1[(size_t)bir * 256 + c0 + e] + X2[(size_t)nrj * 256 + c0 + e] + eeb[c0 + e];
                v.u[e] = f2bf(fmaxf(x, 0.f));
            }
            *(short8*)&U[row * 512 + ((c0 * 2) ^ ((row & 7) << 4))] = v.s;
        }
    }
    __syncthreads();
    // phase 4: WfPB(U) + p-epi -> T  (acc carries from phase 3)
    gemmT(U, WfPB, acc, wv, l);
#pragma unroll
    for (int mt = 0; mt < 2; ++mt) {
        int col0 = 32 * wv + 16 * mt + 4 * g;
        f32x4 pbv = *(const f32x4*)&prb1[col0];
#pragma unroll
        for (int nt = 0; nt < 4; ++nt) {
            int row = 16 * nt + l15;
            f32x4 pv;
#pragma unroll
            for (int q = 0; q < 4; ++q) pv[q] = fmaxf(acc[mt][nt][q] + pbv[q], 0.f);
            pack_store(T, row, col0, pv);
        }
    }
    __syncthreads();
    // phase 5: out = p @ prW2 + prb2. Wave wv: m-tile (wv&3), n-tiles {2*(wv>>2)..+1}
    const int mtf = wv & 3, ntb = (wv >> 2) * 2;
    f32x4 acc3[2];
    acc3[0] = (f32x4){0.f, 0.f, 0.f, 0.f};
    acc3[1] = (f32x4){0.f, 0.f, 0.f, 0.f};
    for (int kt = 0; kt < 8; ++kt) {
        short8 wfr = *(const short8*)(WfP2 + (size_t)((kt * 4 + mtf) * 64 + l) * 8);
#pragma unroll
        for (int n2 = 0; n2 < 2; ++n2) {
            short8 bfr = load_afrag<512>(T, 16 * (ntb + n2) + l15, kt, g);
            acc3[n2] = __builtin_amdgcn_mfma_f32_16x16x32_bf16(wfr, bfr, acc3[n2], 0, 0, 0);
        }
    }
    int col0 = 16 * mtf + 4 * g;
    f32x4 pb2 = *(const f32x4*)&prb2[col0];
#pragma unroll
    for (int n2 = 0; n2 < 2; ++n2) {
        int row = 16 * (ntb + n2) + l15;
        f32x4 o;
#pragma unroll
        for (int q = 0; q < 4; ++q) o[q] = acc3[n2][q] + pb2[q];
        *(f32x4*)&out[(size_t)(ebase + row * 16) * 64 + col0] = o;
    }
}

// ---------------- host ----------------
extern "C" void kernel_launch(void* const* d_in, const int* in_sizes, int n_in,
                              void* d_out, int out_size, void* d_ws, size_t ws_size,
                              hipStream_t stream)
{
    (void)in_sizes; (void)n_in; (void)out_size; (void)ws_size;
    const float* node_rep = (const float*)d_in[0];
    const float* neW   = (const float*)d_in[1];
    const float* neb   = (const float*)d_in[2];
    const float* eeW   = (const float*)d_in[3];
    const float* eeb   = (const float*)d_in[4];
    const float* npW1  = (const float*)d_in[5];
    const float* npb1  = (const float*)d_in[6];
    const float* npW2  = (const float*)d_in[7];
    const float* npb2  = (const float*)d_in[8];
    const float* ep0W1 = (const float*)d_in[9];
    const float* ep0b1 = (const float*)d_in[10];
    const float* ep0W2 = (const float*)d_in[11];
    const float* ep0b2 = (const float*)d_in[12];
    const float* ep1W1 = (const float*)d_in[13];
    const float* ep1b1 = (const float*)d_in[14];
    const float* ep1W2 = (const float*)d_in[15];
    const float* ep1b2 = (const float*)d_in[16];
    const float* prW1  = (const float*)d_in[17];
    const float* prb1  = (const float*)d_in[18];
    const float* prW2  = (const float*)d_in[19];
    const float* prb2  = (const float*)d_in[20];

    char* ws = (char*)d_ws;
    unsigned short* wsu = (unsigned short*)ws;
    auto wfull = [&](int i) { return (const unsigned short*)(ws + (size_t)i * WF_SZ); };
    unsigned short* node_enc = (unsigned short*)(ws + OFF_NENC);
    float* X1   = (float*)(ws + OFF_X1);
    float* X2   = (float*)(ws + OFF_X2);
    float* E1b  = (float*)(ws + OFF_E1);
    float* E2   = (float*)(ws + OFF_E2);
    float* NE1  = (float*)(ws + OFF_NE1);
    float* agg  = (float*)(ws + OFF_AGG);
    unsigned char* img = (unsigned char*)(ws + OFF_IMG);
    const unsigned short* neWf  = (const unsigned short*)(ws + OFF_NEW);
    const unsigned short* eeW1f = (const unsigned short*)(ws + OFF_EE1);
    const unsigned short* eeW2f = (const unsigned short*)(ws + OFF_EE2);
    const unsigned short* prW2f = (const unsigned short*)(ws + OFF_PW2);

    kconv<<<dim3(1920), dim3(64), 0, stream>>>(ep0W1, ep0W2, ep1W1, ep1W2, prW1, prW2,
                                               npW1, npW2, neW, eeW, wsu);
    knode12<<<dim3(64), dim3(256), 0, stream>>>(node_rep, neb, ep0b1, neWf, eeW1f, eeW2f,
                                                wfull(6), wfull(7), wfull(10),
                                                node_enc, X1, X2, E1b, E2, NE1);
    kstep1<<<dim3(2048), dim3(512), 0, stream>>>(X1, X2, eeb, E1b, E2, ep0b2,
                                                 wfull(0), wfull(1), img, agg);
    knode3<<<dim3(64), dim3(256), 0, stream>>>(node_enc, agg, NE1, npb1, npb2, ep1b1,
                                               wfull(8), wfull(9), wfull(11),
                                               wfull(12), wfull(13), E1b, E2);
    kstep2pred<<<dim3(2048), dim3(512), 0, stream>>>(X1, X2, eeb, E1b, E2, ep1b2,
                                                     wfull(2), wfull(3), wfull(4), wfull(5),
                                                     prW2f, prb1, prb2, img, (float*)d_out);
}